// Round 2
// baseline (1859.548 us; speedup 1.0000x reference)
//
#include <hip/hip_runtime.h>
#include <math.h>

// Neural Turing Machine forward, fully fused persistent kernel.
// Grid: 256 blocks x 512 threads; each block owns G=2 batch elements and
// runs all T=64 steps with state in LDS. No inter-block communication.
//
// z-GEMM layout: threads split into 2 k-halves (hf = tid>>8, 148 rows each);
// each thread owns 4 consecutive output columns for BOTH batch elements and
// loads weights as float4 (perfect coalescing, no duplicate loads). Partials
// are summed in the LSTM-gate phase (zp[0] + zp[1]).

#define NSLOT  256
#define MU     32
#define MPAD   33      // +1 pad: avoids 32-bank conflicts on M rows
#define TSTEPS 64
#define EPSF   1e-8f

__device__ __forceinline__ float sigf(float x){ return 1.0f/(1.0f + expf(-x)); }
__device__ __forceinline__ float softplusf_(float x){ return fmaxf(x,0.0f) + log1pf(expf(-fabsf(x))); }

__device__ __forceinline__ float wred_sum(float v){
  #pragma unroll
  for (int m = 32; m >= 1; m >>= 1) v += __shfl_xor(v, m, 64);
  return v;
}
__device__ __forceinline__ float wred_max(float v){
  #pragma unroll
  for (int m = 32; m >= 1; m >>= 1) v = fmaxf(v, __shfl_xor(v, m, 64));
  return v;
}

// Block-level reduction over the 256 threads of batch-slot g2 (waves 0-3 for
// g2=0, waves 4-7 for g2=1). Caller passes a DISTINCT red buffer per call
// site so no leading barrier is needed (buffer's previous use is separated
// by interleaving barriers). Must be called by ALL 512 threads.
__device__ __forceinline__ float grp_red_sum(float v, float* red, int wave, int lane, int g2){
  v = wred_sum(v);
  if (lane == 0) red[wave] = v;
  __syncthreads();
  return red[4*g2] + red[4*g2+1] + red[4*g2+2] + red[4*g2+3];
}
__device__ __forceinline__ float grp_red_max(float v, float* red, int wave, int lane, int g2){
  v = wred_max(v);
  if (lane == 0) red[wave] = v;
  __syncthreads();
  return fmaxf(fmaxf(red[4*g2], red[4*g2+1]), fmaxf(red[4*g2+2], red[4*g2+3]));
}

struct Smem {
  float M[2][NSLOT][MPAD];   // memory, padded rows           67.6 KB
  float zp[2][2][1024];      // z partials [khalf][g][col]    16   KB
  float h[2][256];
  float c[2][256];
  float hob[2][140];         // [read ho(38) | write wo(102)]
  float xcat[2][40];         // [x(8) | R(32)]
  float wr[2][NSLOT];        // read weights state
  float ww[2][NSLOT];        // write weights state
  float wg[2][2][NSLOT];     // shift-conv scratch [head][g][slot]
  float k[2][2][MU];         // key buffer [head][g][m]
  float E[2][MU];
  float A[2][MU];
  float R[2][MU];
  float hpart[2][2][140];    // head GEMM partials [khalf][g][col]
  float rpart[2][8][MU];     // read-vector partials [g][chunk][m]
  float red[3][8];           // per-site reduction buffers
};

// NTM addressing for one head. ho: 38 raw outputs for this (g2). wst:
// previous weights (updated in place). Mg: this g2's memory base.
// head = 0 (read) / 1 (write) selects private k/wg buffers.
__device__ void address_head(int g2, int n2, int wave, int lane, int head,
                             const float* ho, float* wst, const float* Mg,
                             Smem& s)
{
  // per-head scalars, computed redundantly by every thread (LDS broadcast reads)
  float beta  = softplusf_(ho[32]);
  float gg    = sigf(ho[33]);
  float r0 = ho[34], r1 = ho[35], r2 = ho[36];
  float m3 = fmaxf(r0, fmaxf(r1, r2));
  float e0 = expf(r0-m3), e1 = expf(r1-m3), e2 = expf(r2-m3);
  float inv3 = 1.0f/(e0+e1+e2);
  float s0 = e0*inv3, s1 = e1*inv3, s2 = e2*inv3;
  float gamma = 1.0f + softplusf_(ho[37]);

  float* kbuf  = &s.k[head][g2][0];
  float* wgbuf = &s.wg[head][g2][0];

  if (n2 < MU) kbuf[n2] = tanhf(ho[n2]);
  __syncthreads();

  float kn = 0.0f;
  #pragma unroll
  for (int m = 0; m < MU; ++m){ float kv = kbuf[m]; kn = fmaf(kv, kv, kn); }
  kn = sqrtf(kn);

  // cosine similarity for this thread's slot n2
  const float* Mr = Mg + n2*MPAD;
  float dot = 0.0f, mm = 0.0f;
  #pragma unroll
  for (int m = 0; m < MU; ++m){ float mv = Mr[m]; dot = fmaf(mv, kbuf[m], dot); mm = fmaf(mv, mv, mm); }
  float sim = dot / (sqrtf(mm)*kn + EPSF);

  // content softmax over 256 slots
  float bs = beta * sim;
  float mx = grp_red_max(bs, s.red[0], wave, lane, g2);
  float ex = expf(bs - mx);
  float sm = grp_red_sum(ex, s.red[1], wave, lane, g2);
  float wc = ex / sm;

  // interpolate with previous weights, publish for shift conv
  float wgv = fmaf(gg, wc, (1.0f - gg)*wst[n2]);
  wgbuf[n2] = wgv;
  __syncthreads();

  // circular shift conv: w_s[i] = s0*wg[i+1] + s1*wg[i] + s2*wg[i-1]
  float ws = s0*wgbuf[(n2+1)&255] + s1*wgbuf[n2] + s2*wgbuf[(n2-1)&255];

  // sharpen + normalize
  float wp = powf(ws, gamma);
  float sp = grp_red_sum(wp, s.red[2], wave, lane, g2);
  wst[n2] = wp / (sp + EPSF);
}

__global__ __launch_bounds__(512)
void ntm_fused(const float* __restrict__ X,
               const float* __restrict__ Wk,   const float* __restrict__ Wr,
               const float* __restrict__ Lb,
               const float* __restrict__ rW,   const float* __restrict__ rb,
               const float* __restrict__ wW,   const float* __restrict__ wb,
               const float* __restrict__ oW,   const float* __restrict__ ob,
               const float* __restrict__ rInit,
               const float* __restrict__ wrI,  const float* __restrict__ wwI,
               float* __restrict__ Y)
{
  __shared__ Smem s;

  const int tid  = threadIdx.x;
  const int g2   = tid >> 8;        // batch slot within block (0/1)
  const int n2   = tid & 255;       // unit / slot / column-group index
  const int wave = tid >> 6;
  const int lane = tid & 63;
  const int hf   = g2;              // reused as k-half index in split GEMMs
  const int bB   = blockIdx.x * 2;  // first batch element of this block

  // ---------------- init state ----------------
  {
    for (int m = 0; m < MU; ++m) s.M[g2][n2][m] = 1e-6f;
    s.h[g2][n2] = 0.0f;
    s.c[g2][n2] = 0.0f;
    if (n2 < MU) s.R[g2][n2] = tanhf(rInit[n2]);
    // initial weight softmaxes (serial per thread, init-only, broadcast reads)
    float mx = -1e30f;
    for (int i = 0; i < NSLOT; ++i) mx = fmaxf(mx, wrI[i]);
    float sm = 0.0f;
    for (int i = 0; i < NSLOT; ++i) sm += expf(wrI[i] - mx);
    s.wr[g2][n2] = expf(wrI[n2] - mx) / sm;
    mx = -1e30f;
    for (int i = 0; i < NSLOT; ++i) mx = fmaxf(mx, wwI[i]);
    sm = 0.0f;
    for (int i = 0; i < NSLOT; ++i) sm += expf(wwI[i] - mx);
    s.ww[g2][n2] = expf(wwI[n2] - mx) / sm;
  }
  __syncthreads();

  // ---------------- time loop ----------------
  for (int t = 0; t < TSTEPS; ++t) {
    // x_cat = [x(8) | R(32)] for both batch slots
    if (n2 < 40) {
      s.xcat[g2][n2] = (n2 < 8) ? X[((bB + g2)*TSTEPS + t)*8 + n2]
                                : s.R[g2][n2 - 8];
    }
    __syncthreads();

    // ---- z = x_cat@Wk + h@Wr + b ; k-split halves, float4 columns ----
    // half 0: Wk rows 0..39 + Wr rows 0..107; half 1: Wr rows 108..255.
    {
      const int c0 = n2 * 4;
      float a0x=0.f,a0y=0.f,a0z=0.f,a0w=0.f;   // g=0
      float a1x=0.f,a1y=0.f,a1z=0.f,a1w=0.f;   // g=1
      if (hf == 0) {
        #pragma unroll 4
        for (int i = 0; i < 40; ++i) {
          float4 w = *(const float4*)&Wk[i*1024 + c0];
          float x0 = s.xcat[0][i], x1 = s.xcat[1][i];
          a0x=fmaf(w.x,x0,a0x); a0y=fmaf(w.y,x0,a0y); a0z=fmaf(w.z,x0,a0z); a0w=fmaf(w.w,x0,a0w);
          a1x=fmaf(w.x,x1,a1x); a1y=fmaf(w.y,x1,a1y); a1z=fmaf(w.z,x1,a1z); a1w=fmaf(w.w,x1,a1w);
        }
        #pragma unroll 4
        for (int i = 0; i < 108; ++i) {
          float4 w = *(const float4*)&Wr[i*1024 + c0];
          float h0 = s.h[0][i], h1 = s.h[1][i];
          a0x=fmaf(w.x,h0,a0x); a0y=fmaf(w.y,h0,a0y); a0z=fmaf(w.z,h0,a0z); a0w=fmaf(w.w,h0,a0w);
          a1x=fmaf(w.x,h1,a1x); a1y=fmaf(w.y,h1,a1y); a1z=fmaf(w.z,h1,a1z); a1w=fmaf(w.w,h1,a1w);
        }
        // add bias once (half 0 only)
        float4 b = *(const float4*)&Lb[c0];
        a0x+=b.x; a0y+=b.y; a0z+=b.z; a0w+=b.w;
        a1x+=b.x; a1y+=b.y; a1z+=b.z; a1w+=b.w;
      } else {
        #pragma unroll 4
        for (int i = 108; i < 256; ++i) {
          float4 w = *(const float4*)&Wr[i*1024 + c0];
          float h0 = s.h[0][i], h1 = s.h[1][i];
          a0x=fmaf(w.x,h0,a0x); a0y=fmaf(w.y,h0,a0y); a0z=fmaf(w.z,h0,a0z); a0w=fmaf(w.w,h0,a0w);
          a1x=fmaf(w.x,h1,a1x); a1y=fmaf(w.y,h1,a1y); a1z=fmaf(w.z,h1,a1z); a1w=fmaf(w.w,h1,a1w);
        }
      }
      float* z0 = &s.zp[hf][0][c0];
      float* z1 = &s.zp[hf][1][c0];
      z0[0]=a0x; z0[1]=a0y; z0[2]=a0z; z0[3]=a0w;
      z1[0]=a1x; z1[1]=a1y; z1[2]=a1z; z1[3]=a1w;
    }
    __syncthreads();

    // ---- LSTM gates (keras order i,f,g,o); Z==h since |h|<1<CLIP ----
    {
      float zi = s.zp[0][g2][n2      ] + s.zp[1][g2][n2      ];
      float zf = s.zp[0][g2][n2 + 256] + s.zp[1][g2][n2 + 256];
      float zg = s.zp[0][g2][n2 + 512] + s.zp[1][g2][n2 + 512];
      float zo = s.zp[0][g2][n2 + 768] + s.zp[1][g2][n2 + 768];
      float cn = sigf(zf)*s.c[g2][n2] + sigf(zi)*tanhf(zg);
      float hn = sigf(zo)*tanhf(cn);
      s.c[g2][n2] = cn;
      s.h[g2][n2] = hn;
    }
    __syncthreads();

    // ---- head outputs: ho = h @ [read_W | write_W] (140 cols, k-split) ----
    if (n2 < 140) {
      const float* Wp; int stride, cc;
      if (n2 < 38) { Wp = rW; stride = 38;  cc = n2; }
      else         { Wp = wW; stride = 102; cc = n2 - 38; }
      const int i0 = hf * 128;
      float acc0 = 0.0f, acc1 = 0.0f;
      #pragma unroll 4
      for (int ii = 0; ii < 128; ++ii) {
        int i = i0 + ii;
        float wv = Wp[i*stride + cc];
        acc0 = fmaf(wv, s.h[0][i], acc0);
        acc1 = fmaf(wv, s.h[1][i], acc1);
      }
      s.hpart[hf][0][n2] = acc0;
      s.hpart[hf][1][n2] = acc1;
    }
    __syncthreads();
    if (n2 < 140) {
      float bias = (n2 < 38) ? rb[n2] : wb[n2 - 38];
      s.hob[g2][n2] = s.hpart[0][g2][n2] + s.hpart[1][g2][n2] + bias;
    }
    __syncthreads();

    // erase / add vectors (write head raw outputs wo[38:70], wo[70:102])
    if (n2 < MU) {
      s.E[g2][n2] = sigf(s.hob[g2][76 + n2]);
      s.A[g2][n2] = tanhf(s.hob[g2][108 + n2]);
    }

    // ---- read head addressing (pre-write M), then write head addressing ----
    address_head(g2, n2, wave, lane, 0, &s.hob[g2][0],  &s.wr[g2][0],
                 &s.M[g2][0][0], s);
    address_head(g2, n2, wave, lane, 1, &s.hob[g2][38], &s.ww[g2][0],
                 &s.M[g2][0][0], s);

    // ---- R = wr . M  (pre-write M), parallel partials over 8 slot-chunks ----
    {
      const int chunk = n2 >> 5;
      const int m     = n2 & 31;
      const float* Mg = &s.M[g2][0][0];
      const int nb = chunk * 32;
      float acc = 0.0f;
      #pragma unroll 4
      for (int nn = 0; nn < 32; ++nn) {
        int n = nb + nn;
        acc = fmaf(s.wr[g2][n], Mg[n*MPAD + m], acc);
      }
      s.rpart[g2][chunk][m] = acc;
    }
    __syncthreads();
    if (n2 < MU) {
      float r = 0.0f;
      #pragma unroll
      for (int c = 0; c < 8; ++c) r += s.rpart[g2][c][n2];
      s.R[g2][n2] = r;
    }
    __syncthreads();

    // ---- memory write: M = M*(1 - ww*E) + ww*A (thread owns slot n2) ----
    {
      float wwn = s.ww[g2][n2];
      float* Mr = &s.M[g2][n2][0];
      #pragma unroll
      for (int m = 0; m < MU; ++m) {
        Mr[m] = Mr[m] * (1.0f - wwn*s.E[g2][m]) + wwn*s.A[g2][m];
      }
    }

    // ---- output: Y = clip([R | h] @ out_W + b) ----
    {
      const int o = n2 >> 5;   // 0..7
      const int l = n2 & 31;
      float acc = 0.0f;
      #pragma unroll
      for (int ss = 0; ss < 9; ++ss) {
        int j = l + 32*ss;     // covers 0..287 exactly
        float v = (j < 32) ? s.R[g2][j] : s.h[g2][j - 32];
        acc = fmaf(v, oW[j*8 + o], acc);
      }
      #pragma unroll
      for (int m = 16; m >= 1; m >>= 1) acc += __shfl_xor(acc, m, 64);
      if (l == 0) {
        float y = acc + ob[o];
        y = fminf(fmaxf(y, -20.0f), 20.0f);
        Y[((bB + g2)*TSTEPS + t)*8 + o] = y;
      }
    }
    __syncthreads();
  }
}

extern "C" void kernel_launch(void* const* d_in, const int* in_sizes, int n_in,
                              void* d_out, int out_size, void* d_ws, size_t ws_size,
                              hipStream_t stream)
{
  const float* X     = (const float*)d_in[0];
  const float* Wk    = (const float*)d_in[1];
  const float* Wr    = (const float*)d_in[2];
  const float* Lb    = (const float*)d_in[3];
  const float* rW    = (const float*)d_in[4];
  const float* rb    = (const float*)d_in[5];
  const float* wW    = (const float*)d_in[6];
  const float* wb    = (const float*)d_in[7];
  const float* oW    = (const float*)d_in[8];
  const float* ob    = (const float*)d_in[9];
  const float* rInit = (const float*)d_in[10];
  const float* wrI   = (const float*)d_in[11];
  const float* wwI   = (const float*)d_in[12];
  float* Y = (float*)d_out;

  hipLaunchKernelGGL(ntm_fused, dim3(256), dim3(512), 0, stream,
                     X, Wk, Wr, Lb, rW, rb, wW, wb, oW, ob, rInit, wrI, wwI, Y);
}